// Round 13
// baseline (461.446 us; speedup 1.0000x reference)
//
#include <hip/hip_runtime.h>
#include <math.h>

constexpr int NN = 100000;
constexpr int NCHUNK = 128;
constexpr int RROWS  = 12500;   // rows per range (8 ranges); 8-bit LDS counters

using f32x4 = __attribute__((ext_vector_type(4))) float;
using s16x8 = __attribute__((ext_vector_type(8))) short;
using us8   = __attribute__((ext_vector_type(8))) unsigned short;
using us4   = __attribute__((ext_vector_type(4))) unsigned short;

__device__ __forceinline__ unsigned short f2bf(float f) {
    unsigned u = __float_as_uint(f);
    unsigned r = u + 0x7FFFu + ((u >> 16) & 1u);
    return (unsigned short)(r >> 16);
}
__device__ __forceinline__ float bf2f(unsigned short u) {
    return __uint_as_float(((unsigned)u) << 16);
}

// ---------------------------------------------------------------------------
// Weight packing body: W[K x NC] fp32 -> MFMA B-frag order bf16.
// ---------------------------------------------------------------------------
__device__ __forceinline__ void wfrag_body(
    const float* __restrict__ W, short* __restrict__ Wf,
    int K, int NC, int tid)
{
    const int KK = K / 32;
    int lane = tid & 63, f = tid >> 6;
    int ncg = f / KK, kk = f % KK;
    int col = ncg * 16 + (lane & 15);
    int k0  = kk * 32 + 8 * (lane >> 4);
    s16x8 o;
    #pragma unroll
    for (int j = 0; j < 8; ++j)
        o[j] = (col < NC) ? (short)f2bf(W[(size_t)(k0 + j) * NC + col]) : (short)0;
    *reinterpret_cast<s16x8*>(Wf + (size_t)tid * 8) = o;
}

// ---------------------------------------------------------------------------
// MFMA GEMM. AK: 0 = A fp32, 1 = A bf16, 2 = A bf16 with relu(a+b0[k])
// BIASMODE: 0 none, 1 +bias[col]
// ---------------------------------------------------------------------------
template<int K, int WM, int WN, int CB, int AK, bool OBF16, int BIASMODE, bool ORELU>
__global__ __launch_bounds__(WM * WN * 64) void gemm_mfma(
    const void* __restrict__ Ain, const short* __restrict__ Wf,
    const float* __restrict__ bias, const float* __restrict__ b0,
    void* __restrict__ Cout, int M, int NCout)
{
    constexpr int KK = K / 32;
    const int tid = threadIdx.x;
    const int lane = tid & 63, wid = tid >> 6;
    const int wm = wid % WM, wn = wid / WM;
    const int rowBase = blockIdx.x * (WM * 64) + wm * 64;
    const int cfb = wn * CB;
    const int l15 = lane & 15, lh = lane >> 4;

    f32x4 acc[4][CB];
    #pragma unroll
    for (int i = 0; i < 4; ++i)
        #pragma unroll
        for (int j = 0; j < CB; ++j) acc[i][j] = (f32x4)0.f;

    #pragma unroll
    for (int kk = 0; kk < KK; ++kk) {
        const int k0 = kk * 32 + lh * 8;
        s16x8 a[4];
        #pragma unroll
        for (int rb = 0; rb < 4; ++rb) {
            int row = rowBase + rb * 16 + l15;
            row = row < M ? row : M - 1;
            if (AK == 0) {
                const float* ap = (const float*)Ain + (size_t)row * K + k0;
                float4 u = *reinterpret_cast<const float4*>(ap);
                float4 v = *reinterpret_cast<const float4*>(ap + 4);
                a[rb][0] = (short)f2bf(u.x); a[rb][1] = (short)f2bf(u.y);
                a[rb][2] = (short)f2bf(u.z); a[rb][3] = (short)f2bf(u.w);
                a[rb][4] = (short)f2bf(v.x); a[rb][5] = (short)f2bf(v.y);
                a[rb][6] = (short)f2bf(v.z); a[rb][7] = (short)f2bf(v.w);
            } else if (AK == 1) {
                a[rb] = *reinterpret_cast<const s16x8*>((const short*)Ain + (size_t)row * K + k0);
            } else {
                s16x8 s = *reinterpret_cast<const s16x8*>((const short*)Ain + (size_t)row * K + k0);
                float4 ba = *reinterpret_cast<const float4*>(b0 + k0);
                float4 bb = *reinterpret_cast<const float4*>(b0 + k0 + 4);
                float bv[8] = {ba.x, ba.y, ba.z, ba.w, bb.x, bb.y, bb.z, bb.w};
                #pragma unroll
                for (int j = 0; j < 8; ++j) {
                    float fv = bf2f((unsigned short)s[j]) + bv[j];
                    a[rb][j] = (short)f2bf(fmaxf(fv, 0.f));
                }
            }
        }
        s16x8 b[CB];
        #pragma unroll
        for (int cb = 0; cb < CB; ++cb)
            b[cb] = *reinterpret_cast<const s16x8*>(
                Wf + ((size_t)((cfb + cb) * KK + kk) * 64 + lane) * 8);
        #pragma unroll
        for (int rb = 0; rb < 4; ++rb)
            #pragma unroll
            for (int cb = 0; cb < CB; ++cb)
                acc[rb][cb] = __builtin_amdgcn_mfma_f32_16x16x32_bf16(
                    a[rb], b[cb], acc[rb][cb], 0, 0, 0);
    }

    #pragma unroll
    for (int cb = 0; cb < CB; ++cb) {
        int col = (cfb + cb) * 16 + l15;
        if (col >= NCout) continue;
        float bs = (BIASMODE != 0) ? bias[col] : 0.f;
        #pragma unroll
        for (int rb = 0; rb < 4; ++rb) {
            #pragma unroll
            for (int r = 0; r < 4; ++r) {
                int row = rowBase + rb * 16 + lh * 4 + r;
                if (row >= M) continue;
                float v = acc[rb][cb][r];
                if (BIASMODE == 1) v += bs;
                if (ORELU) v = fmaxf(v, 0.f);
                if (OBF16)
                    ((unsigned short*)Cout)[(size_t)row * NCout + col] = f2bf(v);
                else
                    ((float*)Cout)[(size_t)row * NCout + col] = v;
            }
        }
    }
}

// ---------------------------------------------------------------------------
// CSR build: 8-bit packed LDS counters (4 rows per u32 -> 12.5 KB LDS).
// Max per-(chunk,row) count ~ Poisson(0.125) << 255, no carry risk.
// ---------------------------------------------------------------------------
__device__ __forceinline__ void hist_body(
    const int* __restrict__ row, unsigned short* __restrict__ part,
    int E, int chunkE, int chunk, int rowLo, unsigned* lcnt)
{
    for (int i = threadIdx.x; i < RROWS / 4; i += 256) lcnt[i] = 0u;
    __syncthreads();
    const int e0 = chunk * chunkE;
    const int e1 = min(e0 + chunkE, E);
    for (int e = e0 + threadIdx.x; e < e1; e += 256) {
        int lr = row[e] - rowLo;
        if ((unsigned)lr < (unsigned)RROWS)
            atomicAdd(&lcnt[lr >> 2], 1u << ((lr & 3) << 3));
    }
    __syncthreads();
    unsigned* dst = reinterpret_cast<unsigned*>(part + (size_t)chunk * NN + rowLo);
    for (int i = threadIdx.x; i < RROWS / 4; i += 256) {
        unsigned w = lcnt[i];
        dst[2 * i + 0] = (w & 0xFFu) | (((w >> 8) & 0xFFu) << 16);
        dst[2 * i + 1] = ((w >> 16) & 0xFFu) | (((w >> 24) & 0xFFu) << 16);
    }
}

// combo: hist_part (1024 blocks) || weight packing (46 blocks)
__global__ __launch_bounds__(256) void hist_wfrag_combo(
    const int* __restrict__ arow, unsigned short* __restrict__ part,
    int E, int chunkE,
    const float* __restrict__ Wz1, const float* __restrict__ Wz2,
    const float* __restrict__ W0,  const float* __restrict__ W1,
    short* wz1f, short* wz2f, short* w0f, short* w1f)
{
    __shared__ unsigned lcnt[RROWS / 4];
    int b = blockIdx.x;
    if (b < NCHUNK * 8) {
        hist_body(arow, part, E, chunkE, b & (NCHUNK - 1), (b >> 7) * RROWS, lcnt);
    } else {
        int bb = b - NCHUNK * 8;
        if (bb < 8)       wfrag_body(Wz1, wz1f, 128, 128, bb * 256 + threadIdx.x);
        else if (bb < 24) wfrag_body(Wz2, wz2f, 128, 256, (bb - 8) * 256 + threadIdx.x);
        else if (bb < 40) wfrag_body(W0,  w0f,  128, 256, (bb - 24) * 256 + threadIdx.x);
        else {
            int tid = (bb - 40) * 256 + threadIdx.x;
            if (tid < 3 * 8 * 64) wfrag_body(W1, w1f, 256, 40, tid);
        }
    }
}

// standalone scatter with 8-bit packed LDS position counters
__global__ __launch_bounds__(256) void scatter_part(
    const int* __restrict__ row, const int* __restrict__ col,
    const float* __restrict__ val, const int* __restrict__ rp,
    const unsigned short* __restrict__ part, int2* __restrict__ edges,
    int E, int chunkE)
{
    __shared__ unsigned lcnt[RROWS / 4];
    const int chunk = blockIdx.x;
    const int rowLo = blockIdx.y * RROWS;
    for (int i = threadIdx.x; i < RROWS / 4; i += 256) lcnt[i] = 0u;
    __syncthreads();
    const int e0 = chunk * chunkE;
    const int e1 = min(e0 + chunkE, E);
    const unsigned short* choff = part + (size_t)chunk * NN;
    for (int e = e0 + threadIdx.x; e < e1; e += 256) {
        int r = row[e];
        int lr = r - rowLo;
        if ((unsigned)lr < (unsigned)RROWS) {
            unsigned old = atomicAdd(&lcnt[lr >> 2], 1u << ((lr & 3) << 3));
            int local = (int)((old >> ((lr & 3) << 3)) & 0xFFu);
            int p = rp[r] + (int)choff[r] + local;
            edges[p] = make_int2(col[e], __float_as_int(val[e]));
        }
    }
}

// ---------------------------------------------------------------------------
// Scan chain for rp.
// ---------------------------------------------------------------------------
__global__ __launch_bounds__(256) void chunk_scan(
    unsigned short* __restrict__ part, int* __restrict__ cnt)
{
    int r = blockIdx.x * 256 + threadIdx.x;
    if (r >= NN) return;
    int run = 0;
    for (int c0 = 0; c0 < NCHUNK; c0 += 8) {
        int v[8];
        #pragma unroll
        for (int j = 0; j < 8; ++j) v[j] = part[(size_t)(c0 + j) * NN + r];
        #pragma unroll
        for (int j = 0; j < 8; ++j) {
            part[(size_t)(c0 + j) * NN + r] = (unsigned short)run;
            run += v[j];
        }
    }
    cnt[r] = run;
}

__global__ __launch_bounds__(256) void scan_blk(
    const int* __restrict__ cnt, int* __restrict__ rp, int* __restrict__ bsums, int n)
{
    const int t = threadIdx.x;
    const int lane = t & 63, wid = t >> 6;
    const int base = blockIdx.x * 1024 + t * 4;
    int a0 = 0, a1 = 0, a2 = 0, a3 = 0;
    if (base + 3 < n) {
        int4 v = *reinterpret_cast<const int4*>(&cnt[base]);
        a0 = v.x; a1 = v.y; a2 = v.z; a3 = v.w;
    } else {
        if (base + 0 < n) a0 = cnt[base + 0];
        if (base + 1 < n) a1 = cnt[base + 1];
        if (base + 2 < n) a2 = cnt[base + 2];
        if (base + 3 < n) a3 = cnt[base + 3];
    }
    int s0 = a0, s1 = s0 + a1, s2 = s1 + a2, s3 = s2 + a3;
    int v = s3;
    #pragma unroll
    for (int o = 1; o < 64; o <<= 1) {
        int u = __shfl_up(v, o);
        if (lane >= o) v += u;
    }
    __shared__ int wtot[4];
    if (lane == 63) wtot[wid] = v;
    __syncthreads();
    int woff = 0;
    #pragma unroll
    for (int w = 0; w < 4; ++w) if (w < wid) woff += wtot[w];
    int texcl = woff + v - s3;
    if (base + 0 < n) rp[base + 0] = texcl;
    if (base + 1 < n) rp[base + 1] = texcl + s0;
    if (base + 2 < n) rp[base + 2] = texcl + s1;
    if (base + 3 < n) rp[base + 3] = texcl + s2;
    if (t == 255) bsums[blockIdx.x] = woff + v;
}

__global__ void scan_mid(const int* __restrict__ bsums, int* __restrict__ boff, int nb)
{
    if (threadIdx.x == 0 && blockIdx.x == 0) {
        int run = 0;
        for (int b = 0; b < nb; ++b) { boff[b] = run; run += bsums[b]; }
    }
}

__global__ __launch_bounds__(256) void scan_add(
    int* __restrict__ rp, const int* __restrict__ boff, int n, int E)
{
    int i = blockIdx.x * 256 + threadIdx.x;
    if (i < n) rp[i] += boff[i >> 10];
    if (i == 0) rp[n] = E;
}

// ---------------------------------------------------------------------------
// CSR SpMM gather F=128 bf16: 16 lanes/row, us8/lane, edge unroll x8.
// RS: also emit rowsum[r].
// ---------------------------------------------------------------------------
template<bool RS>
__global__ __launch_bounds__(256) void spmm128(
    const int* __restrict__ rp, const int2* __restrict__ edges,
    const unsigned short* __restrict__ mat, unsigned short* __restrict__ out,
    float* __restrict__ rowsum)
{
    int gid = blockIdx.x * 256 + threadIdx.x;
    int r = gid >> 4, sl = gid & 15;
    if (r >= NN) return;
    const int beg = rp[r], end = rp[r + 1];
    float acc[8] = {};
    float vs = 0.f;
    int e = beg;
    for (; e + 7 < end; e += 8) {
        int2 c[8]; float v[8]; us8 f[8];
        #pragma unroll
        for (int k = 0; k < 8; ++k) c[k] = edges[e + k];
        #pragma unroll
        for (int k = 0; k < 8; ++k) {
            v[k] = __int_as_float(c[k].y);
            f[k] = *reinterpret_cast<const us8*>(mat + (size_t)c[k].x * 128 + sl * 8);
        }
        if (RS) vs += v[0] + v[1] + v[2] + v[3] + v[4] + v[5] + v[6] + v[7];
        #pragma unroll
        for (int k = 0; k < 8; ++k)
            #pragma unroll
            for (int j = 0; j < 8; ++j) acc[j] += v[k] * bf2f(f[k][j]);
    }
    for (; e + 3 < end; e += 4) {
        int2 c[4]; float v[4]; us8 f[4];
        #pragma unroll
        for (int k = 0; k < 4; ++k) c[k] = edges[e + k];
        #pragma unroll
        for (int k = 0; k < 4; ++k) {
            v[k] = __int_as_float(c[k].y);
            f[k] = *reinterpret_cast<const us8*>(mat + (size_t)c[k].x * 128 + sl * 8);
        }
        if (RS) vs += v[0] + v[1] + v[2] + v[3];
        #pragma unroll
        for (int k = 0; k < 4; ++k)
            #pragma unroll
            for (int j = 0; j < 8; ++j) acc[j] += v[k] * bf2f(f[k][j]);
    }
    for (; e < end; ++e) {
        int2 cv = edges[e];
        float v = __int_as_float(cv.y);
        if (RS) vs += v;
        us8 f = *reinterpret_cast<const us8*>(mat + (size_t)cv.x * 128 + sl * 8);
        #pragma unroll
        for (int j = 0; j < 8; ++j) acc[j] += v * bf2f(f[j]);
    }
    us8 o;
    #pragma unroll
    for (int j = 0; j < 8; ++j) o[j] = f2bf(acc[j]);
    *reinterpret_cast<us8*>(out + (size_t)r * 128 + sl * 8) = o;
    if (RS && sl == 0) rowsum[r] = vs;
}

// ---------------------------------------------------------------------------
// Fused G2 + sampling, register-only epilogue, fast transcendentals.
// Wave w: col-frags {2w,2w+1} (mean) and {8+2w,8+2w+1} (std) -> same lane.
// ---------------------------------------------------------------------------
__global__ __launch_bounds__(256) void gemm_z_sample(
    const unsigned short* __restrict__ A, const short* __restrict__ Wf,
    const float* __restrict__ bz2, const float* __restrict__ rowsum,
    const float* __restrict__ eps, unsigned short* __restrict__ hout,
    float* __restrict__ partials)
{
    const int tid = threadIdx.x;
    const int lane = tid & 63, wid = tid >> 6;
    const int rowBase = blockIdx.x * 64;
    const int l15 = lane & 15, lh = lane >> 4;

    const int cf[4] = {wid * 2, wid * 2 + 1, 8 + wid * 2, 8 + wid * 2 + 1};

    f32x4 acc[4][4];
    #pragma unroll
    for (int i = 0; i < 4; ++i)
        #pragma unroll
        for (int j = 0; j < 4; ++j) acc[i][j] = (f32x4)0.f;

    #pragma unroll
    for (int kk = 0; kk < 4; ++kk) {
        const int k0 = kk * 32 + lh * 8;
        s16x8 a[4];
        #pragma unroll
        for (int rb = 0; rb < 4; ++rb) {
            int row = rowBase + rb * 16 + l15;
            row = row < NN ? row : NN - 1;
            a[rb] = *reinterpret_cast<const s16x8*>(A + (size_t)row * 128 + k0);
        }
        s16x8 b[4];
        #pragma unroll
        for (int cb = 0; cb < 4; ++cb)
            b[cb] = *reinterpret_cast<const s16x8*>(
                Wf + ((size_t)(cf[cb] * 4 + kk) * 64 + lane) * 8);
        #pragma unroll
        for (int rb = 0; rb < 4; ++rb)
            #pragma unroll
            for (int cb = 0; cb < 4; ++cb)
                acc[rb][cb] = __builtin_amdgcn_mfma_f32_16x16x32_bf16(
                    a[rb], b[cb], acc[rb][cb], 0, 0, 0);
    }

    const float bsm0 = bz2[wid * 32 + l15];
    const float bsm1 = bz2[wid * 32 + 16 + l15];
    const float bss0 = bz2[128 + wid * 32 + l15];
    const float bss1 = bz2[128 + wid * 32 + 16 + l15];
    float p = 0.f;
    #pragma unroll
    for (int rb = 0; rb < 4; ++rb) {
        #pragma unroll
        for (int r = 0; r < 4; ++r) {
            int row = rowBase + rb * 16 + lh * 4 + r;
            if (row >= NN) continue;
            float rs = rowsum[row];
            #pragma unroll
            for (int cb = 0; cb < 2; ++cb) {
                int colm = wid * 32 + cb * 16 + l15;
                float mean = acc[rb][cb][r]     + rs * (cb ? bsm1 : bsm0);
                float sv   = acc[rb][2 + cb][r] + rs * (cb ? bss1 : bss0);
                float ea = __expf(-fabsf(sv));
                float sp = fmaxf(sv, 0.f) + __logf(1.f + ea);
                float sd = sp + 0.01f;
                float e  = eps[(size_t)row * 128 + colm];
                float h  = mean + sd * e;
                hout[(size_t)row * 128 + colm] = f2bf(h);
                p += 0.5f * h * h - 0.5f * e * e - __logf(sd);
            }
        }
    }
    #pragma unroll
    for (int o = 32; o > 0; o >>= 1) p += __shfl_xor(p, o);
    __shared__ float ws[4];
    if (lane == 0) ws[wid] = p;
    __syncthreads();
    if (tid == 0) partials[blockIdx.x] = ws[0] + ws[1] + ws[2] + ws[3];
}

// ---------------------------------------------------------------------------
// CSR SpMM F=40 (bf16) + b1 + log_softmax: 16 lanes/row (10 active).
// ---------------------------------------------------------------------------
__global__ __launch_bounds__(256) void spmm40_lsm(
    const int* __restrict__ rp, const int2* __restrict__ edges,
    const unsigned short* __restrict__ mat, const float* __restrict__ b1,
    float* __restrict__ out)
{
    int gid = blockIdx.x * 256 + threadIdx.x;
    int r = gid >> 4, sl = gid & 15;
    const int beg = rp[r], end = rp[r + 1];
    float4 acc = make_float4(0.f, 0.f, 0.f, 0.f);
    int e = beg;
    for (; e + 3 < end; e += 4) {
        int2 c[4];
        #pragma unroll
        for (int k = 0; k < 4; ++k) c[k] = edges[e + k];
        if (sl < 10) {
            #pragma unroll
            for (int k = 0; k < 4; ++k) {
                float v = __int_as_float(c[k].y);
                us4 m = *reinterpret_cast<const us4*>(mat + (size_t)c[k].x * 40 + sl * 4);
                acc.x += v * bf2f(m[0]); acc.y += v * bf2f(m[1]);
                acc.z += v * bf2f(m[2]); acc.w += v * bf2f(m[3]);
            }
        }
    }
    for (; e < end; ++e) {
        int2 cv = edges[e];
        float v = __int_as_float(cv.y);
        if (sl < 10) {
            us4 m = *reinterpret_cast<const us4*>(mat + (size_t)cv.x * 40 + sl * 4);
            acc.x += v * bf2f(m[0]); acc.y += v * bf2f(m[1]);
            acc.z += v * bf2f(m[2]); acc.w += v * bf2f(m[3]);
        }
    }
    float xv[4] = {-1e30f, -1e30f, -1e30f, -1e30f};
    if (sl < 10) {
        xv[0] = acc.x + b1[sl * 4 + 0]; xv[1] = acc.y + b1[sl * 4 + 1];
        xv[2] = acc.z + b1[sl * 4 + 2]; xv[3] = acc.w + b1[sl * 4 + 3];
    }
    float m = fmaxf(fmaxf(xv[0], xv[1]), fmaxf(xv[2], xv[3]));
    #pragma unroll
    for (int o = 1; o < 16; o <<= 1) m = fmaxf(m, __shfl_xor(m, o, 16));
    float ssum = 0.f;
    #pragma unroll
    for (int k = 0; k < 4; ++k) ssum += (sl < 10) ? __expf(xv[k] - m) : 0.f;
    #pragma unroll
    for (int o = 1; o < 16; o <<= 1) ssum += __shfl_xor(ssum, o, 16);
    if (sl < 10) {
        float lse = m + __logf(ssum);
        float4 o4 = make_float4(xv[0] - lse, xv[1] - lse, xv[2] - lse, xv[3] - lse);
        *reinterpret_cast<float4*>(out + (size_t)r * 40 + sl * 4) = o4;
    }
}

__global__ __launch_bounds__(256) void finalize_l2(
    const float* __restrict__ partials, int np, float* __restrict__ out)
{
    double a = 0.0;
    for (int i = threadIdx.x; i < np; i += 256) a += (double)partials[i];
    #pragma unroll
    for (int o = 32; o > 0; o >>= 1) a += __shfl_xor(a, o);
    __shared__ double ws[4];
    if ((threadIdx.x & 63) == 0) ws[threadIdx.x >> 6] = a;
    __syncthreads();
    if (threadIdx.x == 0)
        out[(size_t)NN * 40] = (float)((ws[0] + ws[1] + ws[2] + ws[3]) / (double)NN);
}

// ---------------------------------------------------------------------------
extern "C" void kernel_launch(void* const* d_in, const int* in_sizes, int n_in,
                              void* d_out, int out_size, void* d_ws, size_t ws_size,
                              hipStream_t stream)
{
    const float* x    = (const float*)d_in[0];
    const int*   arow = (const int*)d_in[1];
    const int*   acol = (const int*)d_in[2];
    const float* aval = (const float*)d_in[3];
    const float* eps  = (const float*)d_in[4];
    const float* Wz1  = (const float*)d_in[5];
    const float* bz1  = (const float*)d_in[6];
    const float* Wz2  = (const float*)d_in[7];
    const float* bz2  = (const float*)d_in[8];
    const float* W0   = (const float*)d_in[9];
    const float* b0   = (const float*)d_in[10];
    const float* W1   = (const float*)d_in[11];
    const float* b1   = (const float*)d_in[12];
    float* out = (float*)d_out;
    const int E = in_sizes[1];

    // ---- workspace ----
    char* p = (char*)d_ws;
    auto alloc = [&](size_t bytes) {
        char* q = p;
        p += (bytes + 15) & ~(size_t)15;
        return (void*)q;
    };
    int2* edges           = (int2*)alloc((size_t)E * 8);
    unsigned short* part  = (unsigned short*)alloc((size_t)NCHUNK * NN * 2); // 25.6 MB
    int*  rp              = (int*)alloc((size_t)(NN + 4) * 4);
    int*  cnt             = (int*)alloc((size_t)NN * 4);
    float* rowsum         = (float*)alloc((size_t)NN * 4);
    int*  bsums           = (int*)alloc(128 * 4);
    int*  boff            = (int*)alloc(128 * 4);
    float* partials       = (float*)alloc(1568 * 4);
    unsigned short* bufT  = (unsigned short*)alloc((size_t)NN * 128 * 2); // t1 / ah / g4
    unsigned short* bufU  = (unsigned short*)alloc((size_t)NN * 128 * 2); // at1 -> h
    unsigned short* bufZ  = (unsigned short*)alloc((size_t)NN * 256 * 2); // s2
    short* wz1f           = (short*)alloc(8  * 4 * 64 * 8 * 2);
    short* wz2f           = (short*)alloc(16 * 4 * 64 * 8 * 2);
    short* w0f            = (short*)alloc(16 * 4 * 64 * 8 * 2);
    short* w1f            = (short*)alloc(3  * 8 * 64 * 8 * 2);

    dim3 blk(256);
    const int nScan = (NN + 1023) / 1024;
    const int gSp = (NN * 16) / 256;                 // 6250
    const int gZ  = (NN + 63) / 64;                  // 1563
    const int chunkE = (E + NCHUNK - 1) / NCHUNK;    // 12500
    const int gHist = NCHUNK * 8;                    // 1024
    const dim3 gPart(NCHUNK, NN / RROWS);            // 128 x 8

    // K1: hist || weight packing (8-bit LDS counters)
    hist_wfrag_combo<<<dim3(gHist + 46), blk, 0, stream>>>(
        arow, part, E, chunkE, Wz1, Wz2, W0, W1, wz1f, wz2f, w0f, w1f);
    // K2: per-row chunk prefix
    chunk_scan<<<dim3((NN + 255) / 256), blk, 0, stream>>>(part, cnt);
    // K3: rp scan chain
    scan_blk<<<dim3(nScan), blk, 0, stream>>>(cnt, rp, bsums, NN);
    scan_mid<<<dim3(1), dim3(64), 0, stream>>>(bsums, boff, nScan);
    scan_add<<<dim3((NN + 256) / 256), blk, 0, stream>>>(rp, boff, NN, E);
    // K4a: scatter (standalone, 8-bit counters, 12.5 KB LDS)
    scatter_part<<<gPart, blk, 0, stream>>>(arow, acol, aval, rp, part, edges, E, chunkE);
    // K4b: G1 (standalone): t1 = relu(x@Wz1 + bz1) -> bufT
    gemm_mfma<128, 2, 2, 4, 0, true, 1, true><<<dim3(782), blk, 0, stream>>>(
        x, wz1f, bz1, nullptr, bufT, NN, 128);
    // K5: at1 = S@t1 -> bufU (+ rowsum)
    spmm128<true><<<dim3(gSp), blk, 0, stream>>>(rp, edges, bufT, bufU, rowsum);
    // K6: z-gemm + sampling: h -> bufU (in place), l2 partials
    gemm_z_sample<<<dim3(gZ), blk, 0, stream>>>(bufU, wz2f, bz2, rowsum, eps, bufU, partials);
    // K7: ah = S@h -> bufT
    spmm128<false><<<dim3(gSp), blk, 0, stream>>>(rp, edges, bufU, bufT, nullptr);
    // K8: s2 = ah@W0 -> bufZ
    gemm_mfma<128, 1, 4, 4, 1, true, 0, false><<<dim3(gZ), blk, 0, stream>>>(
        bufT, w0f, nullptr, nullptr, bufZ, NN, 256);
    // K9: g4 = relu(s2 + b0)@W1 -> bufT (N x 40 bf16)
    gemm_mfma<256, 4, 1, 3, 2, true, 0, false><<<dim3(391), blk, 0, stream>>>(
        bufZ, w1f, nullptr, b0, bufT, NN, 40);
    // K10: spmm3 + b1 + log_softmax -> out
    spmm40_lsm<<<dim3(gSp), blk, 0, stream>>>(rp, edges, bufT, b1, out);
    // K11: l2 scalar
    finalize_l2<<<dim3(1), blk, 0, stream>>>(partials, gZ, out);
}

// Round 14
// 430.965 us; speedup vs baseline: 1.0707x; 1.0707x over previous
//
#include <hip/hip_runtime.h>
#include <math.h>

constexpr int NN = 100000;
constexpr int NCHUNK = 128;
constexpr int RROWS  = 12500;   // rows per range (8 ranges); 8-bit LDS counters

using f32x4 = __attribute__((ext_vector_type(4))) float;
using s16x8 = __attribute__((ext_vector_type(8))) short;
using us8   = __attribute__((ext_vector_type(8))) unsigned short;
using us4   = __attribute__((ext_vector_type(4))) unsigned short;

__device__ __forceinline__ unsigned short f2bf(float f) {
    unsigned u = __float_as_uint(f);
    unsigned r = u + 0x7FFFu + ((u >> 16) & 1u);
    return (unsigned short)(r >> 16);
}
__device__ __forceinline__ float bf2f(unsigned short u) {
    return __uint_as_float(((unsigned)u) << 16);
}

// ---------------------------------------------------------------------------
// Weight packing body: W[K x NC] fp32 -> MFMA B-frag order bf16.
// ---------------------------------------------------------------------------
__device__ __forceinline__ void wfrag_body(
    const float* __restrict__ W, short* __restrict__ Wf,
    int K, int NC, int tid)
{
    const int KK = K / 32;
    int lane = tid & 63, f = tid >> 6;
    int ncg = f / KK, kk = f % KK;
    int col = ncg * 16 + (lane & 15);
    int k0  = kk * 32 + 8 * (lane >> 4);
    s16x8 o;
    #pragma unroll
    for (int j = 0; j < 8; ++j)
        o[j] = (col < NC) ? (short)f2bf(W[(size_t)(k0 + j) * NC + col]) : (short)0;
    *reinterpret_cast<s16x8*>(Wf + (size_t)tid * 8) = o;
}

// ---------------------------------------------------------------------------
// MFMA GEMM body. AK: 0 = A fp32, 1 = A bf16, 2 = A bf16 with relu(a+b0[k])
// BIASMODE: 0 none, 1 +bias[col]
// ---------------------------------------------------------------------------
template<int K, int WM, int WN, int CB, int AK, bool OBF16, int BIASMODE, bool ORELU>
__device__ __forceinline__ void gemm_body(
    int bid, const void* __restrict__ Ain, const short* __restrict__ Wf,
    const float* __restrict__ bias, const float* __restrict__ b0,
    void* __restrict__ Cout, int M, int NCout)
{
    constexpr int KK = K / 32;
    const int tid = threadIdx.x;
    const int lane = tid & 63, wid = tid >> 6;
    const int wm = wid % WM, wn = wid / WM;
    const int rowBase = bid * (WM * 64) + wm * 64;
    const int cfb = wn * CB;
    const int l15 = lane & 15, lh = lane >> 4;

    f32x4 acc[4][CB];
    #pragma unroll
    for (int i = 0; i < 4; ++i)
        #pragma unroll
        for (int j = 0; j < CB; ++j) acc[i][j] = (f32x4)0.f;

    #pragma unroll
    for (int kk = 0; kk < KK; ++kk) {
        const int k0 = kk * 32 + lh * 8;
        s16x8 a[4];
        #pragma unroll
        for (int rb = 0; rb < 4; ++rb) {
            int row = rowBase + rb * 16 + l15;
            row = row < M ? row : M - 1;
            if (AK == 0) {
                const float* ap = (const float*)Ain + (size_t)row * K + k0;
                float4 u = *reinterpret_cast<const float4*>(ap);
                float4 v = *reinterpret_cast<const float4*>(ap + 4);
                a[rb][0] = (short)f2bf(u.x); a[rb][1] = (short)f2bf(u.y);
                a[rb][2] = (short)f2bf(u.z); a[rb][3] = (short)f2bf(u.w);
                a[rb][4] = (short)f2bf(v.x); a[rb][5] = (short)f2bf(v.y);
                a[rb][6] = (short)f2bf(v.z); a[rb][7] = (short)f2bf(v.w);
            } else if (AK == 1) {
                a[rb] = *reinterpret_cast<const s16x8*>((const short*)Ain + (size_t)row * K + k0);
            } else {
                s16x8 s = *reinterpret_cast<const s16x8*>((const short*)Ain + (size_t)row * K + k0);
                float4 ba = *reinterpret_cast<const float4*>(b0 + k0);
                float4 bb = *reinterpret_cast<const float4*>(b0 + k0 + 4);
                float bv[8] = {ba.x, ba.y, ba.z, ba.w, bb.x, bb.y, bb.z, bb.w};
                #pragma unroll
                for (int j = 0; j < 8; ++j) {
                    float fv = bf2f((unsigned short)s[j]) + bv[j];
                    a[rb][j] = (short)f2bf(fmaxf(fv, 0.f));
                }
            }
        }
        s16x8 b[CB];
        #pragma unroll
        for (int cb = 0; cb < CB; ++cb)
            b[cb] = *reinterpret_cast<const s16x8*>(
                Wf + ((size_t)((cfb + cb) * KK + kk) * 64 + lane) * 8);
        #pragma unroll
        for (int rb = 0; rb < 4; ++rb)
            #pragma unroll
            for (int cb = 0; cb < CB; ++cb)
                acc[rb][cb] = __builtin_amdgcn_mfma_f32_16x16x32_bf16(
                    a[rb], b[cb], acc[rb][cb], 0, 0, 0);
    }

    #pragma unroll
    for (int cb = 0; cb < CB; ++cb) {
        int col = (cfb + cb) * 16 + l15;
        if (col >= NCout) continue;
        float bs = (BIASMODE != 0) ? bias[col] : 0.f;
        #pragma unroll
        for (int rb = 0; rb < 4; ++rb) {
            #pragma unroll
            for (int r = 0; r < 4; ++r) {
                int row = rowBase + rb * 16 + lh * 4 + r;
                if (row >= M) continue;
                float v = acc[rb][cb][r];
                if (BIASMODE == 1) v += bs;
                if (ORELU) v = fmaxf(v, 0.f);
                if (OBF16)
                    ((unsigned short*)Cout)[(size_t)row * NCout + col] = f2bf(v);
                else
                    ((float*)Cout)[(size_t)row * NCout + col] = v;
            }
        }
    }
}

template<int K, int WM, int WN, int CB, int AK, bool OBF16, int BIASMODE, bool ORELU>
__global__ __launch_bounds__(WM * WN * 64) void gemm_mfma(
    const void* __restrict__ Ain, const short* __restrict__ Wf,
    const float* __restrict__ bias, const float* __restrict__ b0,
    void* __restrict__ Cout, int M, int NCout)
{
    gemm_body<K, WM, WN, CB, AK, OBF16, BIASMODE, ORELU>(
        blockIdx.x, Ain, Wf, bias, b0, Cout, M, NCout);
}

// ---------------------------------------------------------------------------
// CSR build bodies: 8-bit packed LDS counters (4 rows/u32 -> 12.5 KB LDS).
// Max per-(chunk,row) count ~ Poisson(0.125) << 255, no carry risk.
// ---------------------------------------------------------------------------
__device__ __forceinline__ void hist_body(
    const int* __restrict__ row, unsigned short* __restrict__ part,
    int E, int chunkE, int chunk, int rowLo, unsigned* lcnt)
{
    for (int i = threadIdx.x; i < RROWS / 4; i += 256) lcnt[i] = 0u;
    __syncthreads();
    const int e0 = chunk * chunkE;
    const int e1 = min(e0 + chunkE, E);
    for (int e = e0 + threadIdx.x; e < e1; e += 256) {
        int lr = row[e] - rowLo;
        if ((unsigned)lr < (unsigned)RROWS)
            atomicAdd(&lcnt[lr >> 2], 1u << ((lr & 3) << 3));
    }
    __syncthreads();
    unsigned* dst = reinterpret_cast<unsigned*>(part + (size_t)chunk * NN + rowLo);
    for (int i = threadIdx.x; i < RROWS / 4; i += 256) {
        unsigned w = lcnt[i];
        dst[2 * i + 0] = (w & 0xFFu) | (((w >> 8) & 0xFFu) << 16);
        dst[2 * i + 1] = ((w >> 16) & 0xFFu) | (((w >> 24) & 0xFFu) << 16);
    }
}

__device__ __forceinline__ void scatter_body(
    const int* __restrict__ row, const int* __restrict__ col,
    const float* __restrict__ val, const int* __restrict__ rp,
    const unsigned short* __restrict__ part, int2* __restrict__ edges,
    int E, int chunkE, int chunk, int rowLo, unsigned* lcnt)
{
    for (int i = threadIdx.x; i < RROWS / 4; i += 256) lcnt[i] = 0u;
    __syncthreads();
    const int e0 = chunk * chunkE;
    const int e1 = min(e0 + chunkE, E);
    const unsigned short* choff = part + (size_t)chunk * NN;
    for (int e = e0 + threadIdx.x; e < e1; e += 256) {
        int r = row[e];
        int lr = r - rowLo;
        if ((unsigned)lr < (unsigned)RROWS) {
            unsigned old = atomicAdd(&lcnt[lr >> 2], 1u << ((lr & 3) << 3));
            int local = (int)((old >> ((lr & 3) << 3)) & 0xFFu);
            int p = rp[r] + (int)choff[r] + local;
            edges[p] = make_int2(col[e], __float_as_int(val[e]));
        }
    }
}

// combo 1: hist_part (1024 blocks) || weight packing (46 blocks)
__global__ __launch_bounds__(256) void hist_wfrag_combo(
    const int* __restrict__ arow, unsigned short* __restrict__ part,
    int E, int chunkE,
    const float* __restrict__ Wz1, const float* __restrict__ Wz2,
    const float* __restrict__ W0,  const float* __restrict__ W1,
    short* wz1f, short* wz2f, short* w0f, short* w1f)
{
    __shared__ unsigned lcnt[RROWS / 4];
    int b = blockIdx.x;
    if (b < NCHUNK * 8) {
        hist_body(arow, part, E, chunkE, b & (NCHUNK - 1), (b >> 7) * RROWS, lcnt);
    } else {
        int bb = b - NCHUNK * 8;
        if (bb < 8)       wfrag_body(Wz1, wz1f, 128, 128, bb * 256 + threadIdx.x);
        else if (bb < 24) wfrag_body(Wz2, wz2f, 128, 256, (bb - 8) * 256 + threadIdx.x);
        else if (bb < 40) wfrag_body(W0,  w0f,  128, 256, (bb - 24) * 256 + threadIdx.x);
        else {
            int tid = (bb - 40) * 256 + threadIdx.x;
            if (tid < 3 * 8 * 64) wfrag_body(W1, w1f, 256, 40, tid);
        }
    }
}

// combo 2: scatter_part (1024 blocks) || G1 gemm (782 blocks)
__global__ __launch_bounds__(256) void scatter_g1_combo(
    const int* __restrict__ arow, const int* __restrict__ acol,
    const float* __restrict__ aval, const int* __restrict__ rp,
    const unsigned short* __restrict__ part, int2* __restrict__ edges,
    int E, int chunkE,
    const float* __restrict__ x, const short* __restrict__ wz1f,
    const float* __restrict__ bz1, unsigned short* __restrict__ t1out)
{
    __shared__ unsigned lcnt[RROWS / 4];
    int b = blockIdx.x;
    if (b < NCHUNK * 8) {
        scatter_body(arow, acol, aval, rp, part, edges, E, chunkE,
                     b & (NCHUNK - 1), (b >> 7) * RROWS, lcnt);
    } else {
        gemm_body<128, 2, 2, 4, 0, true, 1, true>(
            b - NCHUNK * 8, x, wz1f, bz1, nullptr, t1out, NN, 128);
    }
}

// ---------------------------------------------------------------------------
// Scan chain for rp.
// ---------------------------------------------------------------------------
__global__ __launch_bounds__(256) void chunk_scan(
    unsigned short* __restrict__ part, int* __restrict__ cnt)
{
    int r = blockIdx.x * 256 + threadIdx.x;
    if (r >= NN) return;
    int run = 0;
    for (int c0 = 0; c0 < NCHUNK; c0 += 8) {
        int v[8];
        #pragma unroll
        for (int j = 0; j < 8; ++j) v[j] = part[(size_t)(c0 + j) * NN + r];
        #pragma unroll
        for (int j = 0; j < 8; ++j) {
            part[(size_t)(c0 + j) * NN + r] = (unsigned short)run;
            run += v[j];
        }
    }
    cnt[r] = run;
}

__global__ __launch_bounds__(256) void scan_blk(
    const int* __restrict__ cnt, int* __restrict__ rp, int* __restrict__ bsums, int n)
{
    const int t = threadIdx.x;
    const int lane = t & 63, wid = t >> 6;
    const int base = blockIdx.x * 1024 + t * 4;
    int a0 = 0, a1 = 0, a2 = 0, a3 = 0;
    if (base + 3 < n) {
        int4 v = *reinterpret_cast<const int4*>(&cnt[base]);
        a0 = v.x; a1 = v.y; a2 = v.z; a3 = v.w;
    } else {
        if (base + 0 < n) a0 = cnt[base + 0];
        if (base + 1 < n) a1 = cnt[base + 1];
        if (base + 2 < n) a2 = cnt[base + 2];
        if (base + 3 < n) a3 = cnt[base + 3];
    }
    int s0 = a0, s1 = s0 + a1, s2 = s1 + a2, s3 = s2 + a3;
    int v = s3;
    #pragma unroll
    for (int o = 1; o < 64; o <<= 1) {
        int u = __shfl_up(v, o);
        if (lane >= o) v += u;
    }
    __shared__ int wtot[4];
    if (lane == 63) wtot[wid] = v;
    __syncthreads();
    int woff = 0;
    #pragma unroll
    for (int w = 0; w < 4; ++w) if (w < wid) woff += wtot[w];
    int texcl = woff + v - s3;
    if (base + 0 < n) rp[base + 0] = texcl;
    if (base + 1 < n) rp[base + 1] = texcl + s0;
    if (base + 2 < n) rp[base + 2] = texcl + s1;
    if (base + 3 < n) rp[base + 3] = texcl + s2;
    if (t == 255) bsums[blockIdx.x] = woff + v;
}

__global__ void scan_mid(const int* __restrict__ bsums, int* __restrict__ boff, int nb)
{
    if (threadIdx.x == 0 && blockIdx.x == 0) {
        int run = 0;
        for (int b = 0; b < nb; ++b) { boff[b] = run; run += bsums[b]; }
    }
}

__global__ __launch_bounds__(256) void scan_add(
    int* __restrict__ rp, const int* __restrict__ boff, int n, int E)
{
    int i = blockIdx.x * 256 + threadIdx.x;
    if (i < n) rp[i] += boff[i >> 10];
    if (i == 0) rp[n] = E;
}

// ---------------------------------------------------------------------------
// CSR SpMM gather F=128 bf16: 16 lanes/row, us8/lane, edge unroll x8.
// RS: also emit rowsum[r].
// ---------------------------------------------------------------------------
template<bool RS>
__global__ __launch_bounds__(256) void spmm128(
    const int* __restrict__ rp, const int2* __restrict__ edges,
    const unsigned short* __restrict__ mat, unsigned short* __restrict__ out,
    float* __restrict__ rowsum)
{
    int gid = blockIdx.x * 256 + threadIdx.x;
    int r = gid >> 4, sl = gid & 15;
    if (r >= NN) return;
    const int beg = rp[r], end = rp[r + 1];
    float acc[8] = {};
    float vs = 0.f;
    int e = beg;
    for (; e + 7 < end; e += 8) {
        int2 c[8]; float v[8]; us8 f[8];
        #pragma unroll
        for (int k = 0; k < 8; ++k) c[k] = edges[e + k];
        #pragma unroll
        for (int k = 0; k < 8; ++k) {
            v[k] = __int_as_float(c[k].y);
            f[k] = *reinterpret_cast<const us8*>(mat + (size_t)c[k].x * 128 + sl * 8);
        }
        if (RS) vs += v[0] + v[1] + v[2] + v[3] + v[4] + v[5] + v[6] + v[7];
        #pragma unroll
        for (int k = 0; k < 8; ++k)
            #pragma unroll
            for (int j = 0; j < 8; ++j) acc[j] += v[k] * bf2f(f[k][j]);
    }
    for (; e + 3 < end; e += 4) {
        int2 c[4]; float v[4]; us8 f[4];
        #pragma unroll
        for (int k = 0; k < 4; ++k) c[k] = edges[e + k];
        #pragma unroll
        for (int k = 0; k < 4; ++k) {
            v[k] = __int_as_float(c[k].y);
            f[k] = *reinterpret_cast<const us8*>(mat + (size_t)c[k].x * 128 + sl * 8);
        }
        if (RS) vs += v[0] + v[1] + v[2] + v[3];
        #pragma unroll
        for (int k = 0; k < 4; ++k)
            #pragma unroll
            for (int j = 0; j < 8; ++j) acc[j] += v[k] * bf2f(f[k][j]);
    }
    for (; e < end; ++e) {
        int2 cv = edges[e];
        float v = __int_as_float(cv.y);
        if (RS) vs += v;
        us8 f = *reinterpret_cast<const us8*>(mat + (size_t)cv.x * 128 + sl * 8);
        #pragma unroll
        for (int j = 0; j < 8; ++j) acc[j] += v * bf2f(f[j]);
    }
    us8 o;
    #pragma unroll
    for (int j = 0; j < 8; ++j) o[j] = f2bf(acc[j]);
    *reinterpret_cast<us8*>(out + (size_t)r * 128 + sl * 8) = o;
    if (RS && sl == 0) rowsum[r] = vs;
}

// ---------------------------------------------------------------------------
// Fused G2 + sampling, register-only epilogue, fast transcendentals.
// Wave w: col-frags {2w,2w+1} (mean) and {8+2w,8+2w+1} (std) -> same lane.
// ---------------------------------------------------------------------------
__global__ __launch_bounds__(256) void gemm_z_sample(
    const unsigned short* __restrict__ A, const short* __restrict__ Wf,
    const float* __restrict__ bz2, const float* __restrict__ rowsum,
    const float* __restrict__ eps, unsigned short* __restrict__ hout,
    float* __restrict__ partials)
{
    const int tid = threadIdx.x;
    const int lane = tid & 63, wid = tid >> 6;
    const int rowBase = blockIdx.x * 64;
    const int l15 = lane & 15, lh = lane >> 4;

    const int cf[4] = {wid * 2, wid * 2 + 1, 8 + wid * 2, 8 + wid * 2 + 1};

    f32x4 acc[4][4];
    #pragma unroll
    for (int i = 0; i < 4; ++i)
        #pragma unroll
        for (int j = 0; j < 4; ++j) acc[i][j] = (f32x4)0.f;

    #pragma unroll
    for (int kk = 0; kk < 4; ++kk) {
        const int k0 = kk * 32 + lh * 8;
        s16x8 a[4];
        #pragma unroll
        for (int rb = 0; rb < 4; ++rb) {
            int row = rowBase + rb * 16 + l15;
            row = row < NN ? row : NN - 1;
            a[rb] = *reinterpret_cast<const s16x8*>(A + (size_t)row * 128 + k0);
        }
        s16x8 b[4];
        #pragma unroll
        for (int cb = 0; cb < 4; ++cb)
            b[cb] = *reinterpret_cast<const s16x8*>(
                Wf + ((size_t)(cf[cb] * 4 + kk) * 64 + lane) * 8);
        #pragma unroll
        for (int rb = 0; rb < 4; ++rb)
            #pragma unroll
            for (int cb = 0; cb < 4; ++cb)
                acc[rb][cb] = __builtin_amdgcn_mfma_f32_16x16x32_bf16(
                    a[rb], b[cb], acc[rb][cb], 0, 0, 0);
    }

    const float bsm0 = bz2[wid * 32 + l15];
    const float bsm1 = bz2[wid * 32 + 16 + l15];
    const float bss0 = bz2[128 + wid * 32 + l15];
    const float bss1 = bz2[128 + wid * 32 + 16 + l15];
    float p = 0.f;
    #pragma unroll
    for (int rb = 0; rb < 4; ++rb) {
        #pragma unroll
        for (int r = 0; r < 4; ++r) {
            int row = rowBase + rb * 16 + lh * 4 + r;
            if (row >= NN) continue;
            float rs = rowsum[row];
            #pragma unroll
            for (int cb = 0; cb < 2; ++cb) {
                int colm = wid * 32 + cb * 16 + l15;
                float mean = acc[rb][cb][r]     + rs * (cb ? bsm1 : bsm0);
                float sv   = acc[rb][2 + cb][r] + rs * (cb ? bss1 : bss0);
                float ea = __expf(-fabsf(sv));
                float sp = fmaxf(sv, 0.f) + __logf(1.f + ea);
                float sd = sp + 0.01f;
                float e  = eps[(size_t)row * 128 + colm];
                float h  = mean + sd * e;
                hout[(size_t)row * 128 + colm] = f2bf(h);
                p += 0.5f * h * h - 0.5f * e * e - __logf(sd);
            }
        }
    }
    #pragma unroll
    for (int o = 32; o > 0; o >>= 1) p += __shfl_xor(p, o);
    __shared__ float ws[4];
    if (lane == 0) ws[wid] = p;
    __syncthreads();
    if (tid == 0) partials[blockIdx.x] = ws[0] + ws[1] + ws[2] + ws[3];
}

// ---------------------------------------------------------------------------
// CSR SpMM F=40 (bf16) + b1 + log_softmax: 16 lanes/row (10 active).
// ---------------------------------------------------------------------------
__global__ __launch_bounds__(256) void spmm40_lsm(
    const int* __restrict__ rp, const int2* __restrict__ edges,
    const unsigned short* __restrict__ mat, const float* __restrict__ b1,
    float* __restrict__ out)
{
    int gid = blockIdx.x * 256 + threadIdx.x;
    int r = gid >> 4, sl = gid & 15;
    const int beg = rp[r], end = rp[r + 1];
    float4 acc = make_float4(0.f, 0.f, 0.f, 0.f);
    int e = beg;
    for (; e + 3 < end; e += 4) {
        int2 c[4];
        #pragma unroll
        for (int k = 0; k < 4; ++k) c[k] = edges[e + k];
        if (sl < 10) {
            #pragma unroll
            for (int k = 0; k < 4; ++k) {
                float v = __int_as_float(c[k].y);
                us4 m = *reinterpret_cast<const us4*>(mat + (size_t)c[k].x * 40 + sl * 4);
                acc.x += v * bf2f(m[0]); acc.y += v * bf2f(m[1]);
                acc.z += v * bf2f(m[2]); acc.w += v * bf2f(m[3]);
            }
        }
    }
    for (; e < end; ++e) {
        int2 cv = edges[e];
        float v = __int_as_float(cv.y);
        if (sl < 10) {
            us4 m = *reinterpret_cast<const us4*>(mat + (size_t)cv.x * 40 + sl * 4);
            acc.x += v * bf2f(m[0]); acc.y += v * bf2f(m[1]);
            acc.z += v * bf2f(m[2]); acc.w += v * bf2f(m[3]);
        }
    }
    float xv[4] = {-1e30f, -1e30f, -1e30f, -1e30f};
    if (sl < 10) {
        xv[0] = acc.x + b1[sl * 4 + 0]; xv[1] = acc.y + b1[sl * 4 + 1];
        xv[2] = acc.z + b1[sl * 4 + 2]; xv[3] = acc.w + b1[sl * 4 + 3];
    }
    float m = fmaxf(fmaxf(xv[0], xv[1]), fmaxf(xv[2], xv[3]));
    #pragma unroll
    for (int o = 1; o < 16; o <<= 1) m = fmaxf(m, __shfl_xor(m, o, 16));
    float ssum = 0.f;
    #pragma unroll
    for (int k = 0; k < 4; ++k) ssum += (sl < 10) ? __expf(xv[k] - m) : 0.f;
    #pragma unroll
    for (int o = 1; o < 16; o <<= 1) ssum += __shfl_xor(ssum, o, 16);
    if (sl < 10) {
        float lse = m + __logf(ssum);
        float4 o4 = make_float4(xv[0] - lse, xv[1] - lse, xv[2] - lse, xv[3] - lse);
        *reinterpret_cast<float4*>(out + (size_t)r * 40 + sl * 4) = o4;
    }
}

__global__ __launch_bounds__(256) void finalize_l2(
    const float* __restrict__ partials, int np, float* __restrict__ out)
{
    double a = 0.0;
    for (int i = threadIdx.x; i < np; i += 256) a += (double)partials[i];
    #pragma unroll
    for (int o = 32; o > 0; o >>= 1) a += __shfl_xor(a, o);
    __shared__ double ws[4];
    if ((threadIdx.x & 63) == 0) ws[threadIdx.x >> 6] = a;
    __syncthreads();
    if (threadIdx.x == 0)
        out[(size_t)NN * 40] = (float)((ws[0] + ws[1] + ws[2] + ws[3]) / (double)NN);
}

// ---------------------------------------------------------------------------
extern "C" void kernel_launch(void* const* d_in, const int* in_sizes, int n_in,
                              void* d_out, int out_size, void* d_ws, size_t ws_size,
                              hipStream_t stream)
{
    const float* x    = (const float*)d_in[0];
    const int*   arow = (const int*)d_in[1];
    const int*   acol = (const int*)d_in[2];
    const float* aval = (const float*)d_in[3];
    const float* eps  = (const float*)d_in[4];
    const float* Wz1  = (const float*)d_in[5];
    const float* bz1  = (const float*)d_in[6];
    const float* Wz2  = (const float*)d_in[7];
    const float* bz2  = (const float*)d_in[8];
    const float* W0   = (const float*)d_in[9];
    const float* b0   = (const float*)d_in[10];
    const float* W1   = (const float*)d_in[11];
    const float* b1   = (const float*)d_in[12];
    float* out = (float*)d_out;
    const int E = in_sizes[1];

    // ---- workspace ----
    char* p = (char*)d_ws;
    auto alloc = [&](size_t bytes) {
        char* q = p;
        p += (bytes + 15) & ~(size_t)15;
        return (void*)q;
    };
    int2* edges           = (int2*)alloc((size_t)E * 8);
    unsigned short* part  = (unsigned short*)alloc((size_t)NCHUNK * NN * 2); // 25.6 MB
    int*  rp              = (int*)alloc((size_t)(NN + 4) * 4);
    int*  cnt             = (int*)alloc((size_t)NN * 4);
    float* rowsum         = (float*)alloc((size_t)NN * 4);
    int*  bsums           = (int*)alloc(128 * 4);
    int*  boff            = (int*)alloc(128 * 4);
    float* partials       = (float*)alloc(1568 * 4);
    unsigned short* bufT  = (unsigned short*)alloc((size_t)NN * 128 * 2); // t1 / ah / g4
    unsigned short* bufU  = (unsigned short*)alloc((size_t)NN * 128 * 2); // at1 -> h
    unsigned short* bufZ  = (unsigned short*)alloc((size_t)NN * 256 * 2); // s2
    short* wz1f           = (short*)alloc(8  * 4 * 64 * 8 * 2);
    short* wz2f           = (short*)alloc(16 * 4 * 64 * 8 * 2);
    short* w0f            = (short*)alloc(16 * 4 * 64 * 8 * 2);
    short* w1f            = (short*)alloc(3  * 8 * 64 * 8 * 2);

    dim3 blk(256);
    const int nScan = (NN + 1023) / 1024;
    const int gSp = (NN * 16) / 256;                 // 6250
    const int gZ  = (NN + 63) / 64;                  // 1563
    const int chunkE = (E + NCHUNK - 1) / NCHUNK;    // 12500
    const int gHist = NCHUNK * 8;                    // 1024

    // K1: hist || weight packing (8-bit counters, 12.5 KB LDS)
    hist_wfrag_combo<<<dim3(gHist + 46), blk, 0, stream>>>(
        arow, part, E, chunkE, Wz1, Wz2, W0, W1, wz1f, wz2f, w0f, w1f);
    // K2: per-row chunk prefix
    chunk_scan<<<dim3((NN + 255) / 256), blk, 0, stream>>>(part, cnt);
    // K3: rp scan chain
    scan_blk<<<dim3(nScan), blk, 0, stream>>>(cnt, rp, bsums, NN);
    scan_mid<<<dim3(1), dim3(64), 0, stream>>>(bsums, boff, nScan);
    scan_add<<<dim3((NN + 256) / 256), blk, 0, stream>>>(rp, boff, NN, E);
    // K4: scatter || G1 (t1 = relu(x@Wz1 + bz1) -> bufT)
    scatter_g1_combo<<<dim3(gHist + 782), blk, 0, stream>>>(
        arow, acol, aval, rp, part, edges, E, chunkE, x, wz1f, bz1, bufT);
    // K5: at1 = S@t1 -> bufU (+ rowsum)
    spmm128<true><<<dim3(gSp), blk, 0, stream>>>(rp, edges, bufT, bufU, rowsum);
    // K6: z-gemm + sampling: h -> bufU (in place), l2 partials
    gemm_z_sample<<<dim3(gZ), blk, 0, stream>>>(bufU, wz2f, bz2, rowsum, eps, bufU, partials);
    // K7: ah = S@h -> bufT
    spmm128<false><<<dim3(gSp), blk, 0, stream>>>(rp, edges, bufU, bufT, nullptr);
    // K8: s2 = ah@W0 -> bufZ
    gemm_mfma<128, 1, 4, 4, 1, true, 0, false><<<dim3(gZ), blk, 0, stream>>>(
        bufT, w0f, nullptr, nullptr, bufZ, NN, 256);
    // K9: g4 = relu(s2 + b0)@W1 -> bufT (N x 40 bf16)
    gemm_mfma<256, 4, 1, 3, 2, true, 0, false><<<dim3(391), blk, 0, stream>>>(
        bufZ, w1f, nullptr, b0, bufT, NN, 40);
    // K10: spmm3 + b1 + log_softmax -> out
    spmm40_lsm<<<dim3(gSp), blk, 0, stream>>>(rp, edges, bufT, b1, out);
    // K11: l2 scalar
    finalize_l2<<<dim3(1), blk, 0, stream>>>(partials, gZ, out);
}